// Round 1
// baseline (2034.370 us; speedup 1.0000x reference)
//
#include <hip/hip_runtime.h>

#define EPS 1e-5f

constexpr int NB   = 8;
constexpr int NN   = 2048;
constexpr int DIM  = 128;
constexpr int KNN  = 16;
constexpr int POSH = 64;
constexpr int AH   = 512;   // DIM*4
constexpr int NPTS = NB * NN; // 16384
constexpr float SCALE = 0.08838834764831845f; // 1/sqrt(128)

// ---------------------------------------------------------------------------
// Generic fp32 tiled GEMM: C[M,N] = A[M,K] @ W[K,N]. 64x64 tile, K%32==0.
// ---------------------------------------------------------------------------
__global__ __launch_bounds__(256) void gemm_tile(
    const float* __restrict__ A, const float* __restrict__ W,
    float* __restrict__ C, int M, int N, int K)
{
  __shared__ float As[64][33];
  __shared__ float Ws[32][65];
  const int bm = blockIdx.x * 64, bn = blockIdx.y * 64;
  const int tid = threadIdx.x;
  const int tx = tid & 15, ty = tid >> 4;
  float acc[4][4] = {};
  for (int k0 = 0; k0 < K; k0 += 32) {
#pragma unroll
    for (int i = 0; i < 8; ++i) {
      int e = tid + i * 256;
      As[e >> 5][e & 31] = A[(size_t)(bm + (e >> 5)) * K + k0 + (e & 31)];
    }
#pragma unroll
    for (int i = 0; i < 8; ++i) {
      int e = tid + i * 256;
      Ws[e >> 6][e & 63] = W[(size_t)(k0 + (e >> 6)) * N + bn + (e & 63)];
    }
    __syncthreads();
#pragma unroll
    for (int kk = 0; kk < 32; ++kk) {
      float a[4], w[4];
#pragma unroll
      for (int i = 0; i < 4; ++i) a[i] = As[ty * 4 + i][kk];
#pragma unroll
      for (int j = 0; j < 4; ++j) w[j] = Ws[kk][tx * 4 + j];
#pragma unroll
      for (int i = 0; i < 4; ++i)
#pragma unroll
        for (int j = 0; j < 4; ++j)
          acc[i][j] += a[i] * w[j];
    }
    __syncthreads();
  }
#pragma unroll
  for (int i = 0; i < 4; ++i)
#pragma unroll
    for (int j = 0; j < 4; ++j)
      C[(size_t)(bm + ty * 4 + i) * N + bn + tx * 4 + j] = acc[i][j];
}

// ---------------------------------------------------------------------------
// KNN: one block per (b,i). d2 row in LDS, 16 rounds of argmin with
// lowest-index tie-break (matches jax.lax.top_k semantics on the set).
// ---------------------------------------------------------------------------
__global__ __launch_bounds__(256) void knn_kernel(
    const float* __restrict__ pos, int* __restrict__ idx_out)
{
  __shared__ float dist[NN];
  __shared__ float redv[256];
  __shared__ int   redi[256];
  const int b = blockIdx.x >> 11, i = blockIdx.x & (NN - 1);
  const int tid = threadIdx.x;
  const float* pb = pos + (size_t)b * NN * 3;
  const float xi = pb[i * 3], yi = pb[i * 3 + 1], zi = pb[i * 3 + 2];
  const float sqi = xi * xi + yi * yi + zi * zi;
  for (int j = tid; j < NN; j += 256) {
    float xj = pb[j * 3], yj = pb[j * 3 + 1], zj = pb[j * 3 + 2];
    float sqj = xj * xj + yj * yj + zj * zj;
    float dot = xi * xj + yi * yj + zi * zj;
    dist[j] = sqi + sqj - 2.0f * dot;
  }
  __syncthreads();
  for (int s = 0; s < KNN; ++s) {
    float bv = 3.4e38f; int bi = 1 << 30;
    for (int j = tid; j < NN; j += 256) {
      float v = dist[j];
      if (v < bv) { bv = v; bi = j; }   // increasing j => keeps lowest idx
    }
    redv[tid] = bv; redi[tid] = bi;
    __syncthreads();
    if (tid < 64) {
      float v0 = bv; int i0 = bi;
#pragma unroll
      for (int o = 64; o < 256; o += 64) {
        float ov = redv[tid + o]; int oi = redi[tid + o];
        if (ov < v0 || (ov == v0 && oi < i0)) { v0 = ov; i0 = oi; }
      }
#pragma unroll
      for (int off = 32; off > 0; off >>= 1) {
        float ov = __shfl_down(v0, off);
        int   oi = __shfl_down(i0, off);
        if (ov < v0 || (ov == v0 && oi < i0)) { v0 = ov; i0 = oi; }
      }
      if (tid == 0) {
        idx_out[(size_t)blockIdx.x * KNN + s] = i0;
        dist[i0] = 3.4e38f;
      }
    }
    __syncthreads();
  }
}

// ---------------------------------------------------------------------------
// Fused per-point kernel: gather, pos-MLP, attn-MLP, softmax, aggregate,
// output projection + residual. One block (256 thr) per point.
// ---------------------------------------------------------------------------
__global__ __launch_bounds__(256) void fused_kernel(
    const float* __restrict__ ori_x, const float* __restrict__ pos,
    const float* __restrict__ qkv, const int* __restrict__ knn_idx,
    const float* __restrict__ pos_w1, const float* __restrict__ pos_b1,
    const float* __restrict__ pos_bn_g, const float* __restrict__ pos_bn_b,
    const float* __restrict__ pos_bn_m, const float* __restrict__ pos_bn_v,
    const float* __restrict__ pos_w2, const float* __restrict__ pos_b2,
    const float* __restrict__ attn_w1, const float* __restrict__ attn_b1,
    const float* __restrict__ attn_bn_g, const float* __restrict__ attn_bn_b,
    const float* __restrict__ attn_bn_m, const float* __restrict__ attn_bn_v,
    const float* __restrict__ attn_w2, const float* __restrict__ attn_b2,
    const float* __restrict__ w_out, float* __restrict__ out)
{
  __shared__ float q_s[DIM];            // later reused as agg
  __shared__ float pe_s[KNN][DIM];
  __shared__ float a_s[KNN][DIM];       // later reused as h
  __shared__ float vpe_s[KNN][DIM];
  __shared__ float t1_s[KNN][AH];
  __shared__ float ph_s[KNN][POSH];
  __shared__ float relp[KNN][3];
  __shared__ int   nbr[KNN];

  const int p = blockIdx.x;
  const int b = p >> 11, n = p & (NN - 1);
  const int tid = threadIdx.x;

  if (tid < KNN) nbr[tid] = knn_idx[(size_t)p * KNN + tid];
  if (tid < DIM) q_s[tid] = qkv[(size_t)p * 384 + tid];
  __syncthreads();

  if (tid < KNN * 3) {
    int kk = tid / 3, d = tid - kk * 3;
    int j = nbr[kk];
    relp[kk][d] = pos[((size_t)b * NN + n) * 3 + d] - pos[((size_t)b * NN + j) * 3 + d];
  }
  __syncthreads();

  // pos-MLP hidden: relu(bn(rel_pos @ pos_w1 + b1)) -> [16][64]
  for (int e = tid; e < KNN * POSH; e += 256) {
    int kk = e >> 6, c = e & 63;
    float s = relp[kk][0] * pos_w1[c] + relp[kk][1] * pos_w1[POSH + c]
            + relp[kk][2] * pos_w1[2 * POSH + c] + pos_b1[c];
    float sc = pos_bn_g[c] * rsqrtf(pos_bn_v[c] + EPS);
    s = (s - pos_bn_m[c]) * sc + pos_bn_b[c];
    ph_s[kk][c] = fmaxf(s, 0.0f);
  }
  __syncthreads();

  // pe = ph @ pos_w2 + b2 -> [16][128]
  for (int e = tid; e < KNN * DIM; e += 256) {
    int kk = e >> 7, c = e & 127;
    float s = pos_b2[c];
#pragma unroll 8
    for (int k = 0; k < POSH; ++k) s += ph_s[kk][k] * pos_w2[k * DIM + c];
    pe_s[kk][c] = s;
  }
  __syncthreads();

  // a = q - k_g + pe ; vpe = v_g + pe
  for (int e = tid; e < KNN * DIM; e += 256) {
    int kk = e >> 7, c = e & 127;
    const float* qkv_j = qkv + ((size_t)b * NN + nbr[kk]) * 384;
    float pe = pe_s[kk][c];
    a_s[kk][c]   = q_s[c] - qkv_j[DIM + c] + pe;
    vpe_s[kk][c] = qkv_j[2 * DIM + c] + pe;
  }
  __syncthreads();

  // GEMM1: t1 = relu(bn(a @ attn_w1 + b1))  [16x128]@[128x512]
  {
    const int c0 = tid, c1 = tid + 256;
    float acc0[KNN] = {}, acc1[KNN] = {};
    for (int k = 0; k < DIM; k += 4) {
      float w0[4], w1v[4];
#pragma unroll
      for (int u = 0; u < 4; ++u) {
        w0[u]  = attn_w1[(size_t)(k + u) * AH + c0];
        w1v[u] = attn_w1[(size_t)(k + u) * AH + c1];
      }
#pragma unroll
      for (int kk = 0; kk < KNN; ++kk) {
        float4 av = *(const float4*)&a_s[kk][k];
        acc0[kk] += av.x * w0[0] + av.y * w0[1] + av.z * w0[2] + av.w * w0[3];
        acc1[kk] += av.x * w1v[0] + av.y * w1v[1] + av.z * w1v[2] + av.w * w1v[3];
      }
    }
    float sc0 = attn_bn_g[c0] * rsqrtf(attn_bn_v[c0] + EPS);
    float sh0 = attn_bn_b[c0] - attn_bn_m[c0] * sc0;
    float sc1 = attn_bn_g[c1] * rsqrtf(attn_bn_v[c1] + EPS);
    float sh1 = attn_bn_b[c1] - attn_bn_m[c1] * sc1;
    float bb0 = attn_b1[c0], bb1 = attn_b1[c1];
#pragma unroll
    for (int kk = 0; kk < KNN; ++kk) {
      t1_s[kk][c0] = fmaxf((acc0[kk] + bb0) * sc0 + sh0, 0.0f);
      t1_s[kk][c1] = fmaxf((acc1[kk] + bb1) * sc1 + sh1, 0.0f);
    }
  }
  __syncthreads();

  // GEMM2: h = t1 @ attn_w2 + b2  [16x512]@[512x128], h stored into a_s
  {
    const int c = tid & 127;
    const int kk0 = (tid >> 7) * 8;
    float acc[8] = {};
    for (int k = 0; k < AH; k += 4) {
      float w[4];
#pragma unroll
      for (int u = 0; u < 4; ++u) w[u] = attn_w2[(size_t)(k + u) * DIM + c];
#pragma unroll
      for (int r = 0; r < 8; ++r) {
        float4 tv = *(const float4*)&t1_s[kk0 + r][k];
        acc[r] += tv.x * w[0] + tv.y * w[1] + tv.z * w[2] + tv.w * w[3];
      }
    }
    float b2c = attn_b2[c];
#pragma unroll
    for (int r = 0; r < 8; ++r) a_s[kk0 + r][c] = acc[r] + b2c;
  }
  __syncthreads();

  // softmax over neighbors (axis k) per channel + aggregate
  if (tid < DIM) {
    const int c = tid;
    float hv[KNN];
    float mx = -3.4e38f;
#pragma unroll
    for (int kk = 0; kk < KNN; ++kk) { hv[kk] = a_s[kk][c] * SCALE; mx = fmaxf(mx, hv[kk]); }
    float sum = 0.0f;
#pragma unroll
    for (int kk = 0; kk < KNN; ++kk) { hv[kk] = expf(hv[kk] - mx); sum += hv[kk]; }
    float inv = 1.0f / sum;
    float agg = 0.0f;
#pragma unroll
    for (int kk = 0; kk < KNN; ++kk) agg += hv[kk] * vpe_s[kk][c];
    q_s[c] = agg * inv;
  }
  __syncthreads();

  // out = agg @ w_out + ori_x
  if (tid < DIM) {
    const int c = tid;
    float s = ori_x[(size_t)p * DIM + c];
    for (int k = 0; k < DIM; ++k) s += q_s[k] * w_out[k * DIM + c];
    out[(size_t)p * DIM + c] = s;
  }
}

extern "C" void kernel_launch(void* const* d_in, const int* in_sizes, int n_in,
                              void* d_out, int out_size, void* d_ws, size_t ws_size,
                              hipStream_t stream)
{
  const float* ori_x    = (const float*)d_in[0];
  const float* pos      = (const float*)d_in[1];
  const float* w_in     = (const float*)d_in[2];
  const float* w_qkv    = (const float*)d_in[3];
  const float* w_out    = (const float*)d_in[4];
  const float* pos_w1   = (const float*)d_in[5];
  const float* pos_b1   = (const float*)d_in[6];
  const float* pos_bn_g = (const float*)d_in[7];
  const float* pos_bn_b = (const float*)d_in[8];
  const float* pos_bn_m = (const float*)d_in[9];
  const float* pos_bn_v = (const float*)d_in[10];
  const float* pos_w2   = (const float*)d_in[11];
  const float* pos_b2   = (const float*)d_in[12];
  const float* attn_w1  = (const float*)d_in[13];
  const float* attn_b1  = (const float*)d_in[14];
  const float* attn_bn_g = (const float*)d_in[15];
  const float* attn_bn_b = (const float*)d_in[16];
  const float* attn_bn_m = (const float*)d_in[17];
  const float* attn_bn_v = (const float*)d_in[18];
  const float* attn_w2  = (const float*)d_in[19];
  const float* attn_b2  = (const float*)d_in[20];
  float* out = (float*)d_out;

  float* x   = (float*)d_ws;                       // 16384*128 f32
  float* qkv = x + (size_t)NPTS * DIM;             // 16384*384 f32
  int*   idx = (int*)(qkv + (size_t)NPTS * 3 * DIM); // 16384*16 int

  gemm_tile<<<dim3(NPTS / 64, DIM / 64), 256, 0, stream>>>(ori_x, w_in, x, NPTS, DIM, DIM);
  gemm_tile<<<dim3(NPTS / 64, (3 * DIM) / 64), 256, 0, stream>>>(x, w_qkv, qkv, NPTS, 3 * DIM, DIM);
  knn_kernel<<<NPTS, 256, 0, stream>>>(pos, idx);
  fused_kernel<<<NPTS, 256, 0, stream>>>(ori_x, pos, qkv, idx,
      pos_w1, pos_b1, pos_bn_g, pos_bn_b, pos_bn_m, pos_bn_v, pos_w2, pos_b2,
      attn_w1, attn_b1, attn_bn_g, attn_bn_b, attn_bn_m, attn_bn_v,
      attn_w2, attn_b2, w_out, out);
}

// Round 2
// 541.806 us; speedup vs baseline: 3.7548x; 3.7548x over previous
//
#include <hip/hip_runtime.h>

#define EPS 1e-5f

constexpr int NB   = 8;
constexpr int NN   = 2048;
constexpr int DIM  = 128;
constexpr int KNN  = 16;
constexpr int POSH = 64;
constexpr int AH   = 512;
constexpr int NPTS = NB * NN;
constexpr float SCALE = 0.08838834764831845f; // 1/sqrt(128)

typedef __attribute__((ext_vector_type(8))) short short8;
typedef __attribute__((ext_vector_type(4))) float floatx4;

__device__ __forceinline__ short f2bf(float f) {
  union { float f; unsigned u; } a; a.f = f;
  unsigned u = a.u;
  unsigned r = (u + 0x7fffu + ((u >> 16) & 1u)) >> 16;  // RNE
  return (short)r;
}
__device__ __forceinline__ float bf2f(short s) {
  union { unsigned u; float f; } a; a.u = ((unsigned)(unsigned short)s) << 16;
  return a.f;
}

// ---------------------------------------------------------------------------
// fp32 tiled GEMM: C = A@W (+R). 64x64 tile, K%32==0.
// ---------------------------------------------------------------------------
template <bool RES>
__global__ __launch_bounds__(256) void gemm_tile_t(
    const float* __restrict__ A, const float* __restrict__ W,
    const float* __restrict__ R, float* __restrict__ C, int M, int N, int K)
{
  __shared__ float As[64][33];
  __shared__ float Ws[32][65];
  const int bm = blockIdx.x * 64, bn = blockIdx.y * 64;
  const int tid = threadIdx.x;
  const int tx = tid & 15, ty = tid >> 4;
  float acc[4][4] = {};
  for (int k0 = 0; k0 < K; k0 += 32) {
#pragma unroll
    for (int i = 0; i < 8; ++i) {
      int e = tid + i * 256;
      As[e >> 5][e & 31] = A[(size_t)(bm + (e >> 5)) * K + k0 + (e & 31)];
    }
#pragma unroll
    for (int i = 0; i < 8; ++i) {
      int e = tid + i * 256;
      Ws[e >> 6][e & 63] = W[(size_t)(k0 + (e >> 6)) * N + bn + (e & 63)];
    }
    __syncthreads();
#pragma unroll
    for (int kk = 0; kk < 32; ++kk) {
      float a[4], w[4];
#pragma unroll
      for (int i = 0; i < 4; ++i) a[i] = As[ty * 4 + i][kk];
#pragma unroll
      for (int j = 0; j < 4; ++j) w[j] = Ws[kk][tx * 4 + j];
#pragma unroll
      for (int i = 0; i < 4; ++i)
#pragma unroll
        for (int j = 0; j < 4; ++j)
          acc[i][j] += a[i] * w[j];
    }
    __syncthreads();
  }
#pragma unroll
  for (int i = 0; i < 4; ++i)
#pragma unroll
    for (int j = 0; j < 4; ++j) {
      size_t o = (size_t)(bm + ty * 4 + i) * N + bn + tx * 4 + j;
      C[o] = RES ? (acc[i][j] + R[o]) : acc[i][j];
    }
}

// ---------------------------------------------------------------------------
// KNN: one block per (b,i); 16 argmin rounds, lowest-index tie-break.
// ---------------------------------------------------------------------------
__global__ __launch_bounds__(256) void knn_kernel(
    const float* __restrict__ pos, int* __restrict__ idx_out)
{
  __shared__ float dist[NN];
  __shared__ float redv[256];
  __shared__ int   redi[256];
  const int b = blockIdx.x >> 11, i = blockIdx.x & (NN - 1);
  const int tid = threadIdx.x;
  const float* pb = pos + (size_t)b * NN * 3;
  const float xi = pb[i * 3], yi = pb[i * 3 + 1], zi = pb[i * 3 + 2];
  const float sqi = xi * xi + yi * yi + zi * zi;
  for (int j = tid; j < NN; j += 256) {
    float xj = pb[j * 3], yj = pb[j * 3 + 1], zj = pb[j * 3 + 2];
    float sqj = xj * xj + yj * yj + zj * zj;
    float dot = xi * xj + yi * yj + zi * zj;
    dist[j] = sqi + sqj - 2.0f * dot;
  }
  __syncthreads();
  for (int s = 0; s < KNN; ++s) {
    float bv = 3.4e38f; int bi = 1 << 30;
    for (int j = tid; j < NN; j += 256) {
      float v = dist[j];
      if (v < bv) { bv = v; bi = j; }
    }
    redv[tid] = bv; redi[tid] = bi;
    __syncthreads();
    if (tid < 64) {
      float v0 = bv; int i0 = bi;
#pragma unroll
      for (int o = 64; o < 256; o += 64) {
        float ov = redv[tid + o]; int oi = redi[tid + o];
        if (ov < v0 || (ov == v0 && oi < i0)) { v0 = ov; i0 = oi; }
      }
#pragma unroll
      for (int off = 32; off > 0; off >>= 1) {
        float ov = __shfl_down(v0, off);
        int   oi = __shfl_down(i0, off);
        if (ov < v0 || (ov == v0 && oi < i0)) { v0 = ov; i0 = oi; }
      }
      if (tid == 0) {
        idx_out[(size_t)blockIdx.x * KNN + s] = i0;
        dist[i0] = 3.4e38f;
      }
    }
    __syncthreads();
  }
}

// ---------------------------------------------------------------------------
// Prepack: bf16 XOR-swizzled B-fragment weight layouts + folded BN params.
// Also folds pos_b2 into q-rows and v-rows of qkv:
//   a = q - k_g + (pe0 + pos_b2) == (q + pos_b2) - k_g + pe0
//   vpe = v_g + (pe0 + pos_b2)   == (v_g + pos_b2) + pe0
// ---------------------------------------------------------------------------
__global__ __launch_bounds__(256) void prep_weights(
    const float* __restrict__ attn_w1, const float* __restrict__ attn_w2,
    const float* __restrict__ pos_w2,
    const float* __restrict__ attn_b1, const float* __restrict__ abn_g,
    const float* __restrict__ abn_b, const float* __restrict__ abn_m,
    const float* __restrict__ abn_v,
    const float* __restrict__ pos_b1, const float* __restrict__ pbn_g,
    const float* __restrict__ pbn_b, const float* __restrict__ pbn_m,
    const float* __restrict__ pbn_v,
    short* __restrict__ w1p, short* __restrict__ w2p, short* __restrict__ pw2p,
    float* __restrict__ t1sc, float* __restrict__ t1bi,
    float* __restrict__ phsc, float* __restrict__ phbi)
{
  int t = blockIdx.x * 256 + threadIdx.x;
  if (t < 65536) {
    int n = t >> 7, rest = t & 127, up = rest >> 3, j = rest & 7;
    int k = ((up ^ (n & 15)) << 3) + j;
    w1p[t] = f2bf(attn_w1[(size_t)k * AH + n]);
  } else if (t < 131072) {
    int e = t - 65536;
    int nc = e >> 7;
    int ch = nc >> 7, n = nc & 127;
    int rest = e & 127, up = rest >> 3, j = rest & 7;
    int k = ch * 128 + ((up ^ (n & 15)) << 3) + j;
    w2p[e] = f2bf(attn_w2[(size_t)k * DIM + n]);
  } else if (t < 139264) {
    int e = t - 131072;
    int j = e & 7, l = (e >> 3) & 63, cks = e >> 9;
    int ks = cks & 1, ct = cks >> 1;
    int qq = l >> 4, c = l & 15;
    int k = ks * 32 + qq * 8 + j, n = ct * 16 + c;
    pw2p[e] = f2bf(pos_w2[(size_t)k * DIM + n]);
  } else if (t < 139776) {
    int c = t - 139264;
    float sc = abn_g[c] * rsqrtf(abn_v[c] + EPS);
    t1sc[c] = sc;
    t1bi[c] = (attn_b1[c] - abn_m[c]) * sc + abn_b[c];
  } else if (t < 139840) {
    int c = t - 139776;
    float sc = pbn_g[c] * rsqrtf(pbn_v[c] + EPS);
    phsc[c] = sc;
    phbi[c] = (pos_b1[c] - pbn_m[c]) * sc + pbn_b[c];
  }
}

__global__ __launch_bounds__(256) void fold_b2(
    float* __restrict__ qkvb, const float* __restrict__ pos_b2)
{
  size_t t = (size_t)blockIdx.x * 256 + threadIdx.x;
  if (t < (size_t)NPTS * 128) {
    size_t p = t >> 7; int c = (int)(t & 127);
    float b = pos_b2[c];
    qkvb[p * 384 + c]       += b;
    qkvb[p * 384 + 256 + c] += b;
  }
}

// ---------------------------------------------------------------------------
// Fused MFMA attention: 8 points/block (M=128), 4 waves, 64x64 tile/wave.
// ---------------------------------------------------------------------------
__global__ __launch_bounds__(256, 1) void fused_attn(
    const float* __restrict__ pos, const float* __restrict__ qkv,
    const int* __restrict__ knn_idx,
    const float* __restrict__ pos_w1,
    const short* __restrict__ w1p, const short* __restrict__ w2p,
    const short* __restrict__ pw2p,
    const float* __restrict__ t1sc, const float* __restrict__ t1bi,
    const float* __restrict__ phsc, const float* __restrict__ phbi,
    const float* __restrict__ attn_b2,
    float* __restrict__ agg)
{
  __shared__ short a_s[128 * 136];
  __shared__ short vpe_s[128 * 136];
  __shared__ short t1_s[128 * 136];
  __shared__ short w_s[128 * 128];
  __shared__ float q_s[8 * 128];
  __shared__ float relp_s[128 * 4];
  __shared__ int   nbr_s[128];

  const int tid = threadIdx.x;
  const int lane = tid & 63, w = tid >> 6;
  const int wr = w >> 1, wc = w & 1;
  const int q = lane >> 4, cc = lane & 15;
  const int gp0 = blockIdx.x * 8;
  const int bb = gp0 >> 11;
  const int n0 = gp0 & (NN - 1);

  if (tid < 128) nbr_s[tid] = knn_idx[(size_t)gp0 * KNN + tid];
#pragma unroll
  for (int r2 = 0; r2 < 4; ++r2) {
    int e = tid + r2 * 256;
    q_s[e] = qkv[(size_t)(gp0 + (e >> 7)) * 384 + (e & 127)];
  }
  __syncthreads();
  if (tid < 128) {
    int p = tid >> 4;
    int j = nbr_s[tid];
    const float* pa = pos + ((size_t)bb * NN + n0 + p) * 3;
    const float* pj = pos + ((size_t)bb * NN + j) * 3;
    relp_s[tid * 4 + 0] = pa[0] - pj[0];
    relp_s[tid * 4 + 1] = pa[1] - pj[1];
    relp_s[tid * 4 + 2] = pa[2] - pj[2];
  }
  __syncthreads();

#pragma unroll
  for (int r2 = 0; r2 < 32; ++r2) {
    int e = tid + r2 * 256;
    int row = e >> 6, c = e & 63;
    float lin = relp_s[row * 4] * pos_w1[c] + relp_s[row * 4 + 1] * pos_w1[64 + c]
              + relp_s[row * 4 + 2] * pos_w1[128 + c];
    t1_s[row * 136 + c] = f2bf(fmaxf(lin * phsc[c] + phbi[c], 0.0f));
  }
  __syncthreads();

  floatx4 pe[4][4];
#pragma unroll
  for (int i = 0; i < 4; ++i)
#pragma unroll
    for (int jt = 0; jt < 4; ++jt) pe[i][jt] = (floatx4){0.f, 0.f, 0.f, 0.f};
#pragma unroll
  for (int ks = 0; ks < 2; ++ks) {
    short8 a8[4];
#pragma unroll
    for (int i = 0; i < 4; ++i)
      a8[i] = *(const short8*)(t1_s + ((wr * 4 + i) * 16 + cc) * 136 + ks * 32 + q * 8);
#pragma unroll
    for (int jt = 0; jt < 4; ++jt) {
      short8 b8 = *(const short8*)(pw2p + ((((wc * 4 + jt) * 2 + ks) * 64 + lane) << 3));
#pragma unroll
      for (int i = 0; i < 4; ++i)
        pe[i][jt] = __builtin_amdgcn_mfma_f32_16x16x32_bf16(a8[i], b8, pe[i][jt], 0, 0, 0);
    }
  }

#pragma unroll
  for (int i = 0; i < 4; ++i) {
    int p = wr * 4 + i;
#pragma unroll
    for (int jt = 0; jt < 4; ++jt) {
      int col = (wc * 4 + jt) * 16 + cc;
      float qv = q_s[p * 128 + col];
#pragma unroll
      for (int r = 0; r < 4; ++r) {
        int row = p * 16 + q * 4 + r;
        int j = nbr_s[row];
        const float* kv = qkv + ((size_t)bb * NN + j) * 384;
        float pev = pe[i][jt][r];
        a_s[row * 136 + col]   = f2bf(qv - kv[128 + col] + pev);
        vpe_s[row * 136 + col] = f2bf(kv[256 + col] + pev);
      }
    }
  }
  __syncthreads();

  {
    short8 tmp[8];
    const short8* s1 = (const short8*)(w1p);
#pragma unroll
    for (int it = 0; it < 8; ++it) tmp[it] = s1[tid + it * 256];
#pragma unroll
    for (int it = 0; it < 8; ++it) *(short8*)(w_s + ((tid + it * 256) << 3)) = tmp[it];
  }
  __syncthreads();

  floatx4 hacc[4][4];
#pragma unroll
  for (int i = 0; i < 4; ++i)
#pragma unroll
    for (int jt = 0; jt < 4; ++jt) hacc[i][jt] = (floatx4){0.f, 0.f, 0.f, 0.f};

  for (int ch = 0; ch < 4; ++ch) {
    short8 pf2[8];
    {
      const short8* s2 = (const short8*)(w2p + ch * 16384);
#pragma unroll
      for (int it = 0; it < 8; ++it) pf2[it] = s2[tid + it * 256];
    }
    floatx4 tacc[4][4];
#pragma unroll
    for (int i = 0; i < 4; ++i)
#pragma unroll
      for (int jt = 0; jt < 4; ++jt) tacc[i][jt] = (floatx4){0.f, 0.f, 0.f, 0.f};
#pragma unroll
    for (int ks = 0; ks < 4; ++ks) {
      short8 a8[4], b8[4];
#pragma unroll
      for (int i = 0; i < 4; ++i)
        a8[i] = *(const short8*)(a_s + ((wr * 4 + i) * 16 + cc) * 136 + ks * 32 + q * 8);
#pragma unroll
      for (int jt = 0; jt < 4; ++jt) {
        int np = (wc * 4 + jt) * 16 + cc;
        int up = (ks * 4 + q) ^ cc;
        b8[jt] = *(const short8*)(w_s + np * 128 + up * 8);
      }
#pragma unroll
      for (int i = 0; i < 4; ++i)
#pragma unroll
        for (int jt = 0; jt < 4; ++jt)
          tacc[i][jt] = __builtin_amdgcn_mfma_f32_16x16x32_bf16(a8[i], b8[jt], tacc[i][jt], 0, 0, 0);
    }
#pragma unroll
    for (int jt = 0; jt < 4; ++jt) {
      int colL = (wc * 4 + jt) * 16 + cc;
      int colG = ch * 128 + colL;
      float sc = t1sc[colG], bi = t1bi[colG];
#pragma unroll
      for (int i = 0; i < 4; ++i)
#pragma unroll
        for (int r = 0; r < 4; ++r) {
          int row = (wr * 4 + i) * 16 + q * 4 + r;
          t1_s[row * 136 + colL] = f2bf(fmaxf(tacc[i][jt][r] * sc + bi, 0.0f));
        }
    }
    __syncthreads();
#pragma unroll
    for (int it = 0; it < 8; ++it) *(short8*)(w_s + ((tid + it * 256) << 3)) = pf2[it];
    __syncthreads();
    short8 pf1[8];
    if (ch < 3) {
      const short8* s1 = (const short8*)(w1p + (ch + 1) * 16384);
#pragma unroll
      for (int it = 0; it < 8; ++it) pf1[it] = s1[tid + it * 256];
    }
#pragma unroll
    for (int ks = 0; ks < 4; ++ks) {
      short8 a8[4], b8[4];
#pragma unroll
      for (int i = 0; i < 4; ++i)
        a8[i] = *(const short8*)(t1_s + ((wr * 4 + i) * 16 + cc) * 136 + ks * 32 + q * 8);
#pragma unroll
      for (int jt = 0; jt < 4; ++jt) {
        int np = (wc * 4 + jt) * 16 + cc;
        int up = (ks * 4 + q) ^ cc;
        b8[jt] = *(const short8*)(w_s + np * 128 + up * 8);
      }
#pragma unroll
      for (int i = 0; i < 4; ++i)
#pragma unroll
        for (int jt = 0; jt < 4; ++jt)
          hacc[i][jt] = __builtin_amdgcn_mfma_f32_16x16x32_bf16(a8[i], b8[jt], hacc[i][jt], 0, 0, 0);
    }
    __syncthreads();
    if (ch < 3) {
#pragma unroll
      for (int it = 0; it < 8; ++it) *(short8*)(w_s + ((tid + it * 256) << 3)) = pf1[it];
      __syncthreads();
    }
  }

#pragma unroll
  for (int i = 0; i < 4; ++i) {
    int p = wr * 4 + i;
#pragma unroll
    for (int jt = 0; jt < 4; ++jt) {
      int col = (wc * 4 + jt) * 16 + cc;
      float b2v = attn_b2[col];
      float v0[4], mx = -3.4e38f;
#pragma unroll
      for (int r = 0; r < 4; ++r) {
        v0[r] = (hacc[i][jt][r] + b2v) * SCALE;
        mx = fmaxf(mx, v0[r]);
      }
      mx = fmaxf(mx, __shfl_xor(mx, 16));
      mx = fmaxf(mx, __shfl_xor(mx, 32));
      float ex[4], sum = 0.f;
#pragma unroll
      for (int r = 0; r < 4; ++r) { ex[r] = __expf(v0[r] - mx); sum += ex[r]; }
      sum += __shfl_xor(sum, 16);
      sum += __shfl_xor(sum, 32);
      float inv = 1.0f / sum;
      float part = 0.f;
#pragma unroll
      for (int r = 0; r < 4; ++r) {
        int row = p * 16 + q * 4 + r;
        part += ex[r] * bf2f(vpe_s[row * 136 + col]);
      }
      part += __shfl_xor(part, 16);
      part += __shfl_xor(part, 32);
      if (q == 0) agg[(size_t)(gp0 + p) * DIM + col] = part * inv;
    }
  }
}

extern "C" void kernel_launch(void* const* d_in, const int* in_sizes, int n_in,
                              void* d_out, int out_size, void* d_ws, size_t ws_size,
                              hipStream_t stream)
{
  const float* ori_x    = (const float*)d_in[0];
  const float* pos      = (const float*)d_in[1];
  const float* w_in     = (const float*)d_in[2];
  const float* w_qkv    = (const float*)d_in[3];
  const float* w_out    = (const float*)d_in[4];
  const float* pos_w1   = (const float*)d_in[5];
  const float* pos_b1   = (const float*)d_in[6];
  const float* pos_bn_g = (const float*)d_in[7];
  const float* pos_bn_b = (const float*)d_in[8];
  const float* pos_bn_m = (const float*)d_in[9];
  const float* pos_bn_v = (const float*)d_in[10];
  const float* pos_w2   = (const float*)d_in[11];
  const float* pos_b2   = (const float*)d_in[12];
  const float* attn_w1  = (const float*)d_in[13];
  const float* attn_b1  = (const float*)d_in[14];
  const float* attn_bn_g = (const float*)d_in[15];
  const float* attn_bn_b = (const float*)d_in[16];
  const float* attn_bn_m = (const float*)d_in[17];
  const float* attn_bn_v = (const float*)d_in[18];
  const float* attn_w2  = (const float*)d_in[19];
  const float* attn_b2  = (const float*)d_in[20];
  float* out = (float*)d_out;

  float* x    = (float*)d_ws;                          // reused as agg
  float* qkvb = x + (size_t)NPTS * DIM;
  int*   idx  = (int*)(qkvb + (size_t)NPTS * 3 * DIM);
  short* w1p  = (short*)(idx + (size_t)NPTS * KNN);
  short* w2p  = w1p + 65536;
  short* pw2p = w2p + 65536;
  float* t1sc = (float*)(pw2p + 8192);
  float* t1bi = t1sc + 512;
  float* phsc = t1bi + 512;
  float* phbi = phsc + 64;

  prep_weights<<<547, 256, 0, stream>>>(attn_w1, attn_w2, pos_w2,
      attn_b1, attn_bn_g, attn_bn_b, attn_bn_m, attn_bn_v,
      pos_b1, pos_bn_g, pos_bn_b, pos_bn_m, pos_bn_v,
      w1p, w2p, pw2p, t1sc, t1bi, phsc, phbi);
  gemm_tile_t<false><<<dim3(NPTS / 64, DIM / 64), 256, 0, stream>>>(
      ori_x, w_in, nullptr, x, NPTS, DIM, DIM);
  gemm_tile_t<false><<<dim3(NPTS / 64, (3 * DIM) / 64), 256, 0, stream>>>(
      x, w_qkv, nullptr, qkvb, NPTS, 3 * DIM, DIM);
  fold_b2<<<(NPTS * 128 + 255) / 256, 256, 0, stream>>>(qkvb, pos_b2);
  knn_kernel<<<NPTS, 256, 0, stream>>>(pos, idx);
  fused_attn<<<NPTS / 8, 256, 0, stream>>>(pos, qkvb, idx, pos_w1,
      w1p, w2p, pw2p, t1sc, t1bi, phsc, phbi, attn_b2, x);
  gemm_tile_t<true><<<dim3(NPTS / 64, DIM / 64), 256, 0, stream>>>(
      x, w_out, ori_x, out, NPTS, DIM, DIM);
}